// Round 2
// baseline (397.070 us; speedup 1.0000x reference)
//
#include <hip/hip_runtime.h>
#include <hip/hip_fp16.h>

// Problem constants (from reference)
constexpr int B        = 2;
constexpr int N_IN     = 262144;
constexpr int D        = 32;
constexpr int N_OUT    = 65536;
constexpr int K        = 4;
constexpr int NK       = 9;
constexpr int P        = B * N_OUT * K;        // 524288 output points
constexpr int PPB      = N_OUT * K;            // 262144 points per batch
constexpr size_t XTOT  = (size_t)B * N_IN * D; // 16,777,216 feature elements
constexpr int NPH      = 4;                    // table tiles: 65536 rows = 4.2 MB

typedef _Float16 half2v __attribute__((ext_vector_type(2)));
typedef _Float16 half8v __attribute__((ext_vector_type(8)));
typedef float    f4v    __attribute__((ext_vector_type(4)));

// ---------------- fused pre-pass: fp16 feature table + packed fp16 coords ---
__global__ __launch_bounds__(256) void prep_kernel(
    const float* __restrict__ x,   _Float16* __restrict__ xh,
    const float* __restrict__ cin, half2v*   __restrict__ cp)
{
    const int tid  = blockIdx.x * 256 + threadIdx.x;       // 0 .. 2M-1
    const size_t i = (size_t)tid * 8;
    const f4v a = __builtin_nontemporal_load(reinterpret_cast<const f4v*>(x + i));
    const f4v b = __builtin_nontemporal_load(reinterpret_cast<const f4v*>(x + i) + 1);
    half8v h;
    h[0] = (_Float16)a[0]; h[1] = (_Float16)a[1];
    h[2] = (_Float16)a[2]; h[3] = (_Float16)a[3];
    h[4] = (_Float16)b[0]; h[5] = (_Float16)b[1];
    h[6] = (_Float16)b[2]; h[7] = (_Float16)b[3];
    *reinterpret_cast<half8v*>(xh + i) = h;
    if (tid < B * N_IN) {
        half2v c;
        c[0] = (_Float16)cin[tid];
        c[1] = (_Float16)cin[B * N_IN + tid];
        cp[tid] = c;
    }
}

// ---------------- non-uniform-sigma correctness path (not hit by bench) ------
__device__ void slow_point(
    int p, int cbase, const _Float16* __restrict__ xb,
    const half2v* __restrict__ cpack, const float* __restrict__ coords_out,
    const float* __restrict__ sigma, const int* __restrict__ nidx,
    float* __restrict__ out)
{
    const float cox = coords_out[p];
    const float coy = coords_out[P + p];
    const int* __restrict__ ip = nidx + (size_t)p * NK;
    int id[NK]; float d2[NK];
    #pragma unroll
    for (int t = 0; t < NK; ++t) id[t] = ip[t];
    #pragma unroll
    for (int t = 0; t < NK; ++t) {
        const half2v c = cpack[cbase + id[t]];
        const float dx = cox - (float)c[0], dy = coy - (float)c[1];
        d2[t] = dx * dx + dy * dy;
    }
    for (int q = 0; q < 4; ++q) {
        float n[8], d[8], s[8];
        #pragma unroll
        for (int k = 0; k < 8; ++k) {
            n[k] = 0.f; d[k] = 0.f;
            const float g = sigma[q * 8 + k];
            s[k] = 1.0f / (2.0f * g * g);
        }
        #pragma unroll
        for (int t = 0; t < NK; ++t) {
            const half8v f = *reinterpret_cast<const half8v*>(xb + id[t] * D + q * 8);
            #pragma unroll
            for (int k = 0; k < 8; ++k) {
                const float w = __expf(-d2[t] * s[k]);
                n[k] += w * (float)f[k];
                d[k] += w;
            }
        }
        #pragma unroll
        for (int k = 0; k < 8; ++k)
            out[(size_t)p * D + q * 8 + k] = n[k] / (d[k] + 1e-9f);
    }
}

// ---------------- main kernel: persistent grid, phase-tiled gathers ----------
// 1024 blocks x 256 threads, all co-resident (4 blocks/CU at <=128 VGPR).
// Thread owns 2 full points (32 channels each). All weights/offsets are
// precomputed; the feature table is swept in 4 tiles of 4.2 MB so each XCD's
// L2 holds ~one tile per phase -> gather refetch collapses toward compulsory.
__global__ __launch_bounds__(256, 4) void projection_phase_kernel(
    const _Float16* __restrict__ xh,         // (B, N_IN, D) fp16
    const half2v*   __restrict__ cpack,      // (B, N_IN) fp16 pairs
    const float*    __restrict__ coords_out, // (2, P)
    const float*    __restrict__ sigma,      // (D,)
    const int*      __restrict__ nidx,       // (P, NK)
    float*          __restrict__ out)        // (P, D)
{
    const int bid   = blockIdx.x;            // 0..1023
    const int xcd   = bid & 7;
    const int batch = xcd >> 2;              // one batch per XCD half
    const int wb    = (bid >> 3) * 4 + (xcd & 3);   // 0..511 within batch
    const int p0    = batch * PPB + wb * 512 + threadIdx.x;
    const int p1    = p0 + 256;
    const int cbase = batch * N_IN;
    const _Float16* __restrict__ xb = xh + (size_t)cbase * D;

    float s0; bool uni = true;
    {
        const float g = sigma[0];
        s0 = 1.0f / (2.0f * g * g);
        for (int k = 1; k < 32; ++k) uni = uni && (sigma[k] == sigma[0]);
    }
    if (!uni) {   // block-uniform branch; no __syncthreads in main path yet
        slow_point(p0, cbase, xb, cpack, coords_out, sigma, nidx, out);
        slow_point(p1, cbase, xb, cpack, coords_out, sigma, nidx, out);
        return;
    }

    // ---- setup: idx, weights, den (phase-independent) ----
    int   off0[NK], off1[NK];
    float w0[NK],  w1[NK];
    float den0 = 0.f, den1 = 0.f;
    {
        const float cox0 = __builtin_nontemporal_load(coords_out + p0);
        const float coy0 = __builtin_nontemporal_load(coords_out + P + p0);
        const float cox1 = __builtin_nontemporal_load(coords_out + p1);
        const float coy1 = __builtin_nontemporal_load(coords_out + P + p1);
        const int* __restrict__ ip0 = nidx + (size_t)p0 * NK;
        const int* __restrict__ ip1 = nidx + (size_t)p1 * NK;
        int id0[NK], id1[NK];
        #pragma unroll
        for (int t = 0; t < NK; ++t) {
            id0[t] = __builtin_nontemporal_load(ip0 + t);
            id1[t] = __builtin_nontemporal_load(ip1 + t);
        }
        #pragma unroll
        for (int t = 0; t < NK; ++t) {
            const half2v c0 = cpack[cbase + id0[t]];
            const half2v c1 = cpack[cbase + id1[t]];
            float dx = cox0 - (float)c0[0], dy = coy0 - (float)c0[1];
            w0[t] = __expf(-(dx * dx + dy * dy) * s0);  den0 += w0[t];
            dx = cox1 - (float)c1[0]; dy = coy1 - (float)c1[1];
            w1[t] = __expf(-(dx * dx + dy * dy) * s0);  den1 += w1[t];
            off0[t] = id0[t] * D;      // element offset; tile = off >> 21
            off1[t] = id1[t] * D;
        }
    }

    float num0[32], num1[32];
    #pragma unroll
    for (int k = 0; k < 32; ++k) { num0[k] = 0.f; num1[k] = 0.f; }

    for (int ph = 0; ph < NPH; ++ph) {
        #pragma unroll
        for (int t = 0; t < NK; ++t) {
            if ((off0[t] >> 21) == ph) {
                const _Float16* fp = xb + off0[t];
                const half8v f0 = *reinterpret_cast<const half8v*>(fp);
                const half8v f1 = *reinterpret_cast<const half8v*>(fp + 8);
                const half8v f2 = *reinterpret_cast<const half8v*>(fp + 16);
                const half8v f3 = *reinterpret_cast<const half8v*>(fp + 24);
                const float w = w0[t];
                #pragma unroll
                for (int k = 0; k < 8; ++k) {
                    num0[k]      += w * (float)f0[k];
                    num0[8 + k]  += w * (float)f1[k];
                    num0[16 + k] += w * (float)f2[k];
                    num0[24 + k] += w * (float)f3[k];
                }
            }
        }
        #pragma unroll
        for (int t = 0; t < NK; ++t) {
            if ((off1[t] >> 21) == ph) {
                const _Float16* fp = xb + off1[t];
                const half8v f0 = *reinterpret_cast<const half8v*>(fp);
                const half8v f1 = *reinterpret_cast<const half8v*>(fp + 8);
                const half8v f2 = *reinterpret_cast<const half8v*>(fp + 16);
                const half8v f3 = *reinterpret_cast<const half8v*>(fp + 24);
                const float w = w1[t];
                #pragma unroll
                for (int k = 0; k < 8; ++k) {
                    num1[k]      += w * (float)f0[k];
                    num1[8 + k]  += w * (float)f1[k];
                    num1[16 + k] += w * (float)f2[k];
                    num1[24 + k] += w * (float)f3[k];
                }
            }
        }
        __syncthreads();   // keep the block's 16 waves phase-convoyed
    }

    const float r0 = 1.0f / (den0 + 1e-9f);
    const float r1 = 1.0f / (den1 + 1e-9f);
    float* op0 = out + (size_t)p0 * D;
    float* op1 = out + (size_t)p1 * D;
    #pragma unroll
    for (int c = 0; c < 8; ++c) {
        f4v o;
        o[0] = num0[4*c] * r0;   o[1] = num0[4*c+1] * r0;
        o[2] = num0[4*c+2] * r0; o[3] = num0[4*c+3] * r0;
        __builtin_nontemporal_store(o, reinterpret_cast<f4v*>(op0) + c);
    }
    #pragma unroll
    for (int c = 0; c < 8; ++c) {
        f4v o;
        o[0] = num1[4*c] * r1;   o[1] = num1[4*c+1] * r1;
        o[2] = num1[4*c+2] * r1; o[3] = num1[4*c+3] * r1;
        __builtin_nontemporal_store(o, reinterpret_cast<f4v*>(op1) + c);
    }
}

// ---------------- fallback: proven fp32 path (if ws too small) ---------------
__global__ __launch_bounds__(256) void projection_kernel_f32(
    const float* __restrict__ x,
    const float* __restrict__ coords_in,
    const float* __restrict__ coords_out,
    const float* __restrict__ sigma,
    const int*   __restrict__ nidx,
    float*       __restrict__ out)
{
    const int tid   = blockIdx.x * 256 + threadIdx.x;
    const int point = tid >> 3;
    const int q     = tid & 7;
    const int b     = point / PPB;
    const int cbase = b * N_IN;

    const float cox = coords_out[point];
    const float coy = coords_out[P + point];

    const float4 sg = *reinterpret_cast<const float4*>(sigma + q * 4);
    const float s0 = 1.0f / (2.0f * sg.x * sg.x);
    const float s1 = 1.0f / (2.0f * sg.y * sg.y);
    const float s2 = 1.0f / (2.0f * sg.z * sg.z);
    const float s3 = 1.0f / (2.0f * sg.w * sg.w);

    float4 num = make_float4(0.f, 0.f, 0.f, 0.f);
    float4 den = make_float4(0.f, 0.f, 0.f, 0.f);
    const int* __restrict__ ip = nidx + (size_t)point * NK;

    #pragma unroll
    for (int nk = 0; nk < NK; ++nk) {
        const int idx = ip[nk];
        const float cx = coords_in[cbase + idx];
        const float cy = coords_in[B * N_IN + cbase + idx];
        const float dx = cox - cx;
        const float dy = coy - cy;
        const float d2 = dx * dx + dy * dy;
        const float4 f = *reinterpret_cast<const float4*>(
            x + (size_t)(cbase + idx) * D + q * 4);
        const float w0 = __expf(-d2 * s0);
        const float w1 = __expf(-d2 * s1);
        const float w2 = __expf(-d2 * s2);
        const float w3 = __expf(-d2 * s3);
        num.x += w0 * f.x;  den.x += w0;
        num.y += w1 * f.y;  den.y += w1;
        num.z += w2 * f.z;  den.z += w2;
        num.w += w3 * f.w;  den.w += w3;
    }

    float4 o;
    o.x = num.x / (den.x + 1e-9f);
    o.y = num.y / (den.y + 1e-9f);
    o.z = num.z / (den.z + 1e-9f);
    o.w = num.w / (den.w + 1e-9f);
    *reinterpret_cast<float4*>(out + (size_t)point * D + q * 4) = o;
}

extern "C" void kernel_launch(void* const* d_in, const int* in_sizes, int n_in,
                              void* d_out, int out_size, void* d_ws, size_t ws_size,
                              hipStream_t stream) {
    const float* x      = (const float*)d_in[0];
    const float* cin    = (const float*)d_in[1];
    const float* cout_  = (const float*)d_in[2];
    const float* sigma  = (const float*)d_in[3];
    const int*   nidx   = (const int*)  d_in[4];
    float*       outp   = (float*)d_out;

    const int block = 256;

    const size_t xh_bytes = XTOT * sizeof(_Float16);            // 33.55 MB
    const size_t cp_bytes = (size_t)B * N_IN * sizeof(half2v);  //  2.10 MB

    if (ws_size >= xh_bytes + cp_bytes) {
        _Float16* xh = (_Float16*)d_ws;
        half2v*   cp = (half2v*)((char*)d_ws + xh_bytes);
        prep_kernel<<<(int)(XTOT / 8 / block), block, 0, stream>>>(x, xh, cin, cp);
        projection_phase_kernel<<<1024, block, 0, stream>>>(
            xh, cp, cout_, sigma, nidx, outp);
    } else {
        const int grid_main = (P * 8) / block;   // 16384
        projection_kernel_f32<<<grid_main, block, 0, stream>>>(
            x, cin, cout_, sigma, nidx, outp);
    }
}